// Round 2
// baseline (6681.680 us; speedup 1.0000x reference)
//
#include <hip/hip_runtime.h>
#include <hip/hip_cooperative_groups.h>
#include <math.h>

namespace cg = cooperative_groups;

#define BATCH 8
#define H 256
#define W 256
#define HW (H*W)
#define TS 32
#define KS 9
#define ITER_N 100

struct GaussW { float g[KS]; };

__device__ __forceinline__ int refl(int i, int n) {
    // jnp.pad mode='reflect': mirror without repeating the edge
    if (i < 0) i = -i;
    if (i >= n) i = 2*n - 2 - i;
    return i;
}

// One persistent cooperative kernel: luma + gauss_rho precompute, 100 diffusion
// iterations with grid-wide sync, and the final 3-channel expand.
// Block = 32x32 output tile, 256 threads (4 px/thread held in registers).
__global__ void __launch_bounds__(256, 2) ced_kernel(
        const float* __restrict__ x, float* __restrict__ out,
        float* __restrict__ ua, float* __restrict__ ub,
        const float* __restrict__ dtp, const float* __restrict__ kp,
        GaussW gw)
{
    cg::grid_group gridg = cg::this_grid();

    __shared__ float su[42][44];                            // u tile + halo 5
    __shared__ float p11[40][42], p12[40][42], p22[40][42]; // products on [-4,36)^2
    __shared__ float v11[32][42], v12[32][42], v22[32][42]; // vertical blur partials

    const int tid = threadIdx.x;
    const int tx0 = blockIdx.x * TS, ty0 = blockIdx.y * TS, b = blockIdx.z;
    const float* xb = x + (size_t)b * 3 * HW;

    // ---- Phase A: luma at reflect-mapped coords -> su; separable blur -> myrho
    for (int i = tid; i < 42*42; i += 256) {
        int ly = i / 42, lx = i - ly*42;
        int gy = refl(ty0 - 5 + ly, H), gx = refl(tx0 - 5 + lx, W);
        int o = gy*W + gx;
        su[ly][lx] = 0.299f*xb[o] + 0.587f*xb[HW + o] + 0.114f*xb[2*HW + o];
    }
    __syncthreads();
    // vertical 9-tap: rows [0,32) of the tile, cols [-4,36)
    for (int i = tid; i < 32*40; i += 256) {
        int r = i / 40, px = i - r*40;
        float a = 0.f;
#pragma unroll
        for (int t = 0; t < KS; ++t) a += gw.g[t] * su[r+1+t][px+1];
        v11[r][px] = a;
    }
    __syncthreads();

    float myrho[4], myu[4];
#pragma unroll
    for (int j = 0; j < 4; ++j) {
        int i = tid + j*256;
        int r = i >> 5, c = i & 31;
        float a = 0.f;
#pragma unroll
        for (int t = 0; t < KS; ++t) a += gw.g[t] * v11[r][c+t];
        myrho[j] = a;
        myu[j] = su[r+5][c+5];   // u0 at own pixel (interior coords are identity-mapped)
    }

    const float dt = *dtp;
    const float kk = *kp;
    const float k2 = kk * kk;

    // publish u0 so neighbors can read our halo in iteration 0
    float* cur = ua;
    float* nxt = ub;
    {
        float* cb = cur + b*HW;
#pragma unroll
        for (int j = 0; j < 4; ++j) {
            int i = tid + j*256;
            int r = i >> 5, c = i & 31;
            cb[(ty0 + r)*W + tx0 + c] = myu[j];
        }
    }
    gridg.sync();

    for (int it = 0; it < ITER_N; ++it) {
        // Phase 1: halo ring from global (zero pad outside image), interior from regs
        const float* ubuf = cur + b*HW;
        for (int i = tid; i < 42*42; i += 256) {
            int ly = i / 42, lx = i - ly*42;
            if (ly >= 5 && ly < 37 && lx >= 5 && lx < 37) continue;
            int gy = ty0 - 5 + ly, gx = tx0 - 5 + lx;
            float v = 0.f;
            if (gy >= 0 && gy < H && gx >= 0 && gx < W) v = ubuf[gy*W + gx];
            su[ly][lx] = v;
        }
#pragma unroll
        for (int j = 0; j < 4; ++j) {
            int i = tid + j*256;
            int r = i >> 5, c = i & 31;
            su[r+5][c+5] = myu[j];
        }
        __syncthreads();

        // Phase 2: Sobel + structure-tensor products at reflect-mapped coords
        for (int i = tid; i < 40*40; i += 256) {
            int py = i / 40, px = i - py*40;
            int ry = refl(ty0 - 4 + py, H), rx = refl(tx0 - 4 + px, W);
            int sy = ry - ty0 + 5, sx = rx - tx0 + 5;
            float a  = su[sy-1][sx-1], b0 = su[sy-1][sx], c0 = su[sy-1][sx+1];
            float d0 = su[sy  ][sx-1],                    e0 = su[sy  ][sx+1];
            float f0 = su[sy+1][sx-1], g0 = su[sy+1][sx], h0 = su[sy+1][sx+1];
            float gxv = (c0 - a) + 2.f*(e0 - d0) + (h0 - f0);
            float gyv = (f0 - a) + 2.f*(g0 - b0) + (h0 - c0);
            p11[py][px] = gxv*gxv;
            p12[py][px] = gxv*gyv;
            p22[py][px] = gyv*gyv;
        }
        __syncthreads();

        // Phase 3: vertical 9-tap blur of the three product planes
        for (int i = tid; i < 32*40; i += 256) {
            int r = i / 40, px = i - r*40;
            float a11 = 0.f, a12 = 0.f, a22 = 0.f;
#pragma unroll
            for (int t = 0; t < KS; ++t) {
                float w = gw.g[t];
                a11 += w * p11[r+t][px];
                a12 += w * p12[r+t][px];
                a22 += w * p22[r+t][px];
            }
            v11[r][px] = a11; v12[r][px] = a12; v22[r][px] = a22;
        }
        __syncthreads();

        // Phase 4: horizontal blur + eigenvalues + diffusion update
        float* nbuf = nxt + b*HW;
#pragma unroll
        for (int j = 0; j < 4; ++j) {
            int i = tid + j*256;
            int r = i >> 5, c = i & 31;
            float s11 = 0.f, s12 = 0.f, s22 = 0.f;
#pragma unroll
            for (int t = 0; t < KS; ++t) {
                float w = gw.g[t];
                s11 += w * v11[r][c+t];
                s12 += w * v12[r][c+t];
                s22 += w * v22[r][c+t];
            }
            float rv = myrho[j];
            s11 -= rv; s12 -= rv; s22 -= rv;
            float df = s11 - s22;
            float tm = sqrtf(df*df + 4.f*s12*s12);
            float sm = s11 + s22;
            float lam1 = 0.5f*(sm + tm);
            float lam2 = 0.5f*(sm - tm);
            float c1 = expf(-(lam1*lam1)/k2);
            float c2 = expf(-(lam2*lam2)/k2);
            float un = myu[j] + dt*(c1*lam1 + c2*lam2);
            myu[j] = un;
            nbuf[(ty0 + r)*W + tx0 + c] = un;
        }
        gridg.sync();
        float* t = cur; cur = nxt; nxt = t;
    }

    // ---- Final expand: u -> 3 identical channels
    float* ob = out + (size_t)b * 3 * HW;
#pragma unroll
    for (int j = 0; j < 4; ++j) {
        int i = tid + j*256;
        int r = i >> 5, c = i & 31;
        int o = (ty0 + r)*W + tx0 + c;
        float v = myu[j];
        ob[o] = v; ob[HW + o] = v; ob[2*HW + o] = v;
    }
}

extern "C" void kernel_launch(void* const* d_in, const int* in_sizes, int n_in,
                              void* d_out, int out_size, void* d_ws, size_t ws_size,
                              hipStream_t stream) {
    const float* x   = (const float*)d_in[0];
    const float* dtp = (const float*)d_in[1];
    const float* kp  = (const float*)d_in[2];
    float* out = (float*)d_out;

    float* ua = (float*)d_ws;
    float* ub = ua + BATCH*HW;

    GaussW gw;
    {
        double s = 0.0, wd[KS];
        for (int i = 0; i < KS; ++i) {
            double xd = (double)i - 4.0;
            wd[i] = exp(-0.5 * (xd/4.0) * (xd/4.0));
            s += wd[i];
        }
        for (int i = 0; i < KS; ++i) gw.g[i] = (float)(wd[i] / s);
    }

    dim3 grid(W/TS, H/TS, BATCH), block(256);
    void* args[] = { (void*)&x, (void*)&out, (void*)&ua, (void*)&ub,
                     (void*)&dtp, (void*)&kp, (void*)&gw };
    hipLaunchCooperativeKernel((const void*)ced_kernel, grid, block, args, 0, stream);
}

// Round 3
// 811.355 us; speedup vs baseline: 8.2352x; 8.2352x over previous
//
#include <hip/hip_runtime.h>
#include <math.h>

#define BATCH 8
#define H 256
#define W 256
#define HW (H*W)
#define KS 9
#define NSTEP 50   // 50 launches x 2 fused iterations = 100

struct GaussW { float g[KS]; };

__device__ __forceinline__ int refl(int i, int n) {
    // jnp.pad mode='reflect': mirror without repeating the edge
    if (i < 0) i = -i;
    if (i >= n) i = 2*n - 2 - i;
    return i;
}

__global__ void luma_kernel(const float* __restrict__ x, float* __restrict__ u0) {
    int idx = blockIdx.x * blockDim.x + threadIdx.x;
    if (idx >= BATCH*HW) return;
    int b = idx / HW;
    int rem = idx - b*HW;
    const float* xb = x + (size_t)b*3*HW + rem;
    u0[idx] = 0.299f*xb[0] + 0.587f*xb[HW] + 0.114f*xb[2*HW];
}

__global__ void vblur_kernel(const float* __restrict__ in, float* __restrict__ out, GaussW gw) {
    int idx = blockIdx.x * blockDim.x + threadIdx.x;
    if (idx >= BATCH*HW) return;
    int b = idx >> 16;
    int y = (idx >> 8) & 255;
    int xx = idx & 255;
    const float* ib = in + b*HW;
    float acc = 0.f;
#pragma unroll
    for (int t = 0; t < KS; ++t)
        acc += gw.g[t] * ib[refl(y - 4 + t, H)*W + xx];
    out[idx] = acc;
}

__global__ void hblur_kernel(const float* __restrict__ in, float* __restrict__ out, GaussW gw) {
    int idx = blockIdx.x * blockDim.x + threadIdx.x;
    if (idx >= BATCH*HW) return;
    int b = idx >> 16;
    int y = (idx >> 8) & 255;
    int xx = idx & 255;
    const float* ib = in + b*HW + y*W;
    float acc = 0.f;
#pragma unroll
    for (int t = 0; t < KS; ++t)
        acc += gw.g[t] * ib[refl(xx - 4 + t, W)];
    out[idx] = acc;
}

// TWO fused diffusion iterations per launch. 32x32 output tile, 512 threads.
// Halo radius 10: load u0 on 52x52; iter-1 produces u1 on the 42x42 window
// (at reflect-mapped in-image coords, zero outside image); iter-2 produces the
// 32x32 tile. LDS phases are overlaid to stay < 64 KB (peak 55.2 KB).
__global__ void __launch_bounds__(512, 4) step2_kernel(
        const float* __restrict__ uin, float* __restrict__ uout,
        const float* __restrict__ rho,
        const float* __restrict__ dtp, const float* __restrict__ kp,
        GaussW gw)
{
    __shared__ float lds[13800];                       // 55200 B peak
    float (*p11)[50] = (float(*)[50])(lds + 0);        // iter1 products 50x50
    float (*p12)[50] = (float(*)[50])(lds + 2500);
    float (*p22)[50] = (float(*)[50])(lds + 5000);     // ..7500
    float (*su )[52] = (float(*)[52])(lds + 7500);     // u0 52x52 ..10204
    float (*v11)[50] = (float(*)[50])(lds + 7500);     // iter1 vblur 42x50 (overlays su after death)
    float (*v12)[50] = (float(*)[50])(lds + 9600);
    float (*v22)[50] = (float(*)[50])(lds + 11700);    // ..13800
    float (*u1 )[42] = (float(*)[42])(lds + 0);        // u after iter1, 42x42 (overlays p, dead)
    float (*q11)[40] = (float(*)[40])(lds + 1800);     // iter2 products 40x40
    float (*q12)[40] = (float(*)[40])(lds + 3400);
    float (*q22)[40] = (float(*)[40])(lds + 5000);     // ..6600
    float (*w11)[40] = (float(*)[40])(lds + 7500);     // iter2 vblur 32x40 (overlays v, dead)
    float (*w12)[40] = (float(*)[40])(lds + 8780);
    float (*w22)[40] = (float(*)[40])(lds + 10060);    // ..11340

    const int tid = threadIdx.x;
    const int X0 = blockIdx.x * 32, Y0 = blockIdx.y * 32, b = blockIdx.z;
    const float* ubuf = uin + b*HW;
    const float* rb   = rho + b*HW;
    const float dt = *dtp;
    const float kk = *kp;
    const float k2 = kk * kk;

    // ---- Phase 1: load u0 window [Y0-10,Y0+42) x [X0-10,X0+42), zero outside image
    for (int i = tid; i < 52*52; i += 512) {
        int ly = i / 52, lx = i - ly*52;
        int gy = Y0 - 10 + ly, gx = X0 - 10 + lx;
        float v = 0.f;
        if (gy >= 0 && gy < H && gx >= 0 && gx < W) v = ubuf[gy*W + gx];
        su[ly][lx] = v;
    }
    __syncthreads();

    // ---- Phase 2: iter1 Sobel products on 50x50 window (reflect-mapped coords)
    // Also pre-read u0 and rho (registers) for the iter1 update, so `su` can die.
    float u0r[4], rhor[4];
#pragma unroll
    for (int j = 0; j < 4; ++j) {
        int i = tid + j*512;
        u0r[j] = 0.f; rhor[j] = 0.f;
        if (i < 42*42) {
            int uy = i / 42, ux = i - uy*42;
            u0r[j] = su[uy+5][ux+5];
            int gy = Y0 - 5 + uy, gx = X0 - 5 + ux;
            if (gy >= 0 && gy < H && gx >= 0 && gx < W) rhor[j] = rb[gy*W + gx];
        }
    }
    for (int i = tid; i < 50*50; i += 512) {
        int py = i / 50, px = i - py*50;
        int ry = refl(Y0 - 9 + py, H), rx = refl(X0 - 9 + px, W);
        int sy = ry - Y0 + 10, sx = rx - X0 + 10;
        float a  = su[sy-1][sx-1], b0 = su[sy-1][sx], c0 = su[sy-1][sx+1];
        float d0 = su[sy  ][sx-1],                    e0 = su[sy  ][sx+1];
        float f0 = su[sy+1][sx-1], g0 = su[sy+1][sx], h0 = su[sy+1][sx+1];
        float gxv = (c0 - a) + 2.f*(e0 - d0) + (h0 - f0);
        float gyv = (f0 - a) + 2.f*(g0 - b0) + (h0 - c0);
        p11[py][px] = gxv*gxv;
        p12[py][px] = gxv*gyv;
        p22[py][px] = gyv*gyv;
    }
    __syncthreads();

    // ---- Phase 3: iter1 vertical blur -> v (rows Y0-5..Y0+36, 42x50). su dies here.
    for (int i = tid; i < 42*50; i += 512) {
        int r = i / 50, c = i - r*50;
        float a11 = 0.f, a12 = 0.f, a22 = 0.f;
#pragma unroll
        for (int t = 0; t < KS; ++t) {
            float w = gw.g[t];
            a11 += w * p11[r+t][c];
            a12 += w * p12[r+t][c];
            a22 += w * p22[r+t][c];
        }
        v11[r][c] = a11; v12[r][c] = a12; v22[r][c] = a22;
    }
    __syncthreads();

    // ---- Phase 4: iter1 horizontal blur + eig + update -> u1 (42x42, zero outside image)
#pragma unroll
    for (int j = 0; j < 4; ++j) {
        int i = tid + j*512;
        if (i < 42*42) {
            int uy = i / 42, ux = i - uy*42;
            int gy = Y0 - 5 + uy, gx = X0 - 5 + ux;
            float val = 0.f;
            if (gy >= 0 && gy < H && gx >= 0 && gx < W) {
                float s11 = 0.f, s12 = 0.f, s22 = 0.f;
#pragma unroll
                for (int t = 0; t < KS; ++t) {
                    float w = gw.g[t];
                    s11 += w * v11[uy][ux+t];
                    s12 += w * v12[uy][ux+t];
                    s22 += w * v22[uy][ux+t];
                }
                float rv = rhor[j];
                s11 -= rv; s12 -= rv; s22 -= rv;
                float df = s11 - s22;
                float tm = sqrtf(df*df + 4.f*s12*s12);
                float sm = s11 + s22;
                float lam1 = 0.5f*(sm + tm);
                float lam2 = 0.5f*(sm - tm);
                float c1 = expf(-(lam1*lam1)/k2);
                float c2 = expf(-(lam2*lam2)/k2);
                val = u0r[j] + dt*(c1*lam1 + c2*lam2);
            }
            u1[uy][ux] = val;
        }
    }
    __syncthreads();

    // ---- Phase 5: iter2 Sobel products on 40x40 window (reflect-mapped), from u1
    for (int i = tid; i < 40*40; i += 512) {
        int py = i / 40, px = i - py*40;
        int ry = refl(Y0 - 4 + py, H), rx = refl(X0 - 4 + px, W);
        int sy = ry - Y0 + 5, sx = rx - X0 + 5;
        float a  = u1[sy-1][sx-1], b0 = u1[sy-1][sx], c0 = u1[sy-1][sx+1];
        float d0 = u1[sy  ][sx-1],                    e0 = u1[sy  ][sx+1];
        float f0 = u1[sy+1][sx-1], g0 = u1[sy+1][sx], h0 = u1[sy+1][sx+1];
        float gxv = (c0 - a) + 2.f*(e0 - d0) + (h0 - f0);
        float gyv = (f0 - a) + 2.f*(g0 - b0) + (h0 - c0);
        q11[py][px] = gxv*gxv;
        q12[py][px] = gxv*gyv;
        q22[py][px] = gyv*gyv;
    }
    __syncthreads();

    // ---- Phase 6: iter2 vertical blur -> w (32x40). v dies here (w overlays it).
    for (int i = tid; i < 32*40; i += 512) {
        int r = i / 40, c = i - r*40;
        float a11 = 0.f, a12 = 0.f, a22 = 0.f;
#pragma unroll
        for (int t = 0; t < KS; ++t) {
            float w = gw.g[t];
            a11 += w * q11[r+t][c];
            a12 += w * q12[r+t][c];
            a22 += w * q22[r+t][c];
        }
        w11[r][c] = a11; w12[r][c] = a12; w22[r][c] = a22;
    }
    __syncthreads();

    // ---- Phase 7: iter2 horizontal blur + eig + update -> global
    float* nbuf = uout + b*HW;
#pragma unroll
    for (int j = 0; j < 2; ++j) {
        int i = tid + j*512;
        int r = i >> 5, c = i & 31;
        float s11 = 0.f, s12 = 0.f, s22 = 0.f;
#pragma unroll
        for (int t = 0; t < KS; ++t) {
            float w = gw.g[t];
            s11 += w * w11[r][c+t];
            s12 += w * w12[r][c+t];
            s22 += w * w22[r][c+t];
        }
        int gidx = (Y0 + r)*W + X0 + c;
        float rv = rb[gidx];
        s11 -= rv; s12 -= rv; s22 -= rv;
        float df = s11 - s22;
        float tm = sqrtf(df*df + 4.f*s12*s12);
        float sm = s11 + s22;
        float lam1 = 0.5f*(sm + tm);
        float lam2 = 0.5f*(sm - tm);
        float c1 = expf(-(lam1*lam1)/k2);
        float c2 = expf(-(lam2*lam2)/k2);
        nbuf[gidx] = u1[r+5][c+5] + dt*(c1*lam1 + c2*lam2);
    }
}

__global__ void expand_kernel(const float* __restrict__ u, float* __restrict__ out) {
    int idx = blockIdx.x * blockDim.x + threadIdx.x;
    if (idx >= BATCH*HW) return;
    int b = idx / HW;
    int rem = idx - b*HW;
    float v = u[idx];
    float* ob = out + (size_t)b*3*HW + rem;
    ob[0] = v; ob[HW] = v; ob[2*HW] = v;
}

extern "C" void kernel_launch(void* const* d_in, const int* in_sizes, int n_in,
                              void* d_out, int out_size, void* d_ws, size_t ws_size,
                              hipStream_t stream) {
    const float* x   = (const float*)d_in[0];
    const float* dtp = (const float*)d_in[1];
    const float* kp  = (const float*)d_in[2];
    float* out = (float*)d_out;

    float* u_a = (float*)d_ws;
    float* u_b = u_a + BATCH*HW;
    float* rho = u_b + BATCH*HW;

    GaussW gw;
    {
        double s = 0.0, wd[KS];
        for (int i = 0; i < KS; ++i) {
            double xd = (double)i - 4.0;
            wd[i] = exp(-0.5 * (xd/4.0) * (xd/4.0));
            s += wd[i];
        }
        for (int i = 0; i < KS; ++i) gw.g[i] = (float)(wd[i] / s);
    }

    dim3 b1(256), g1((BATCH*HW + 255)/256);
    luma_kernel<<<g1, b1, 0, stream>>>(x, u_a);
    vblur_kernel<<<g1, b1, 0, stream>>>(u_a, u_b, gw);   // u_b as tmp
    hblur_kernel<<<g1, b1, 0, stream>>>(u_b, rho, gw);

    dim3 gs(W/32, H/32, BATCH), bs(512);
    float* cur = u_a;
    float* nxt = u_b;
    for (int it = 0; it < NSTEP; ++it) {
        step2_kernel<<<gs, bs, 0, stream>>>(cur, nxt, rho, dtp, kp, gw);
        float* t = cur; cur = nxt; nxt = t;
    }
    expand_kernel<<<g1, b1, 0, stream>>>(cur, out);
}

// Round 4
// 749.583 us; speedup vs baseline: 8.9139x; 1.0824x over previous
//
#include <hip/hip_runtime.h>
#include <math.h>

#define BATCH 8
#define H 256
#define W 256
#define HW (H*W)
#define KS 9
#define NSTEP 50   // 50 launches x 2 fused iterations = 100

struct GaussW { float g[KS]; };

__device__ __forceinline__ int refl(int i, int n) {
    if (i < 0) i = -i;
    if (i >= n) i = 2*n - 2 - i;
    return i;
}

__device__ __forceinline__ float4 ld4s(const float* p) { return *(const float4*)p; }
__device__ __forceinline__ void st4s(float* p, float4 v) { *(float4*)p = v; }
__device__ __forceinline__ float4 f4mul(float a, float4 x) {
    return make_float4(a*x.x, a*x.y, a*x.z, a*x.w);
}
__device__ __forceinline__ float4 f4fma(float a, float4 x, float4 y) {
    return make_float4(fmaf(a,x.x,y.x), fmaf(a,x.y,y.y), fmaf(a,x.z,y.z), fmaf(a,x.w,y.w));
}

// ---------------- pre/post kernels ----------------
__global__ void luma_kernel(const float* __restrict__ x, float* __restrict__ u0) {
    int idx = blockIdx.x * blockDim.x + threadIdx.x;
    if (idx >= BATCH*HW) return;
    int b = idx / HW;
    int rem = idx - b*HW;
    const float* xb = x + (size_t)b*3*HW + rem;
    u0[idx] = 0.299f*xb[0] + 0.587f*xb[HW] + 0.114f*xb[2*HW];
}

__global__ void vblur_kernel(const float* __restrict__ in, float* __restrict__ out, GaussW gw) {
    int idx = blockIdx.x * blockDim.x + threadIdx.x;
    if (idx >= BATCH*HW) return;
    int b = idx >> 16;
    int y = (idx >> 8) & 255;
    int xx = idx & 255;
    const float* ib = in + b*HW;
    float acc = 0.f;
#pragma unroll
    for (int t = 0; t < KS; ++t)
        acc += gw.g[t] * ib[refl(y - 4 + t, H)*W + xx];
    out[idx] = acc;
}

__global__ void hblur_kernel(const float* __restrict__ in, float* __restrict__ out, GaussW gw) {
    int idx = blockIdx.x * blockDim.x + threadIdx.x;
    if (idx >= BATCH*HW) return;
    int b = idx >> 16;
    int y = (idx >> 8) & 255;
    int xx = idx & 255;
    const float* ib = in + b*HW + y*W;
    float acc = 0.f;
#pragma unroll
    for (int t = 0; t < KS; ++t)
        acc += gw.g[t] * ib[refl(xx - 4 + t, W)];
    out[idx] = acc;
}

__global__ void expand_kernel(const float* __restrict__ u, float* __restrict__ out) {
    int idx = blockIdx.x * blockDim.x + threadIdx.x;
    if (idx >= BATCH*HW) return;
    int b = idx / HW;
    int rem = idx - b*HW;
    float v = u[idx];
    float* ob = out + (size_t)b*3*HW + rem;
    ob[0] = v; ob[HW] = v; ob[2*HW] = v;
}

// ---------------- register-sliding vertical 9-tap blur strip ----------------
// Computes N consecutive output rows (one float4 column group) of
// V[r] = sum_t g[t] * P[r+t], all b128 LDS accesses.
template<int N>
__device__ __forceinline__ void vblur_strip(const float* __restrict__ P, float* __restrict__ V,
                                            int qoff, int r0, const GaussW gw, int stride) {
    const float* s = P + r0*stride + qoff;
    float4 w0 = ld4s(s); s += stride;
    float4 w1 = ld4s(s); s += stride;
    float4 w2 = ld4s(s); s += stride;
    float4 w3 = ld4s(s); s += stride;
    float4 w4 = ld4s(s); s += stride;
    float4 w5 = ld4s(s); s += stride;
    float4 w6 = ld4s(s); s += stride;
    float4 w7 = ld4s(s); s += stride;
    float* d = V + r0*stride + qoff;
#pragma unroll
    for (int j = 0; j < N; ++j) {
        float4 w8 = ld4s(s); s += stride;
        float4 o = f4mul(gw.g[0], w0);
        o = f4fma(gw.g[1], w1, o);
        o = f4fma(gw.g[2], w2, o);
        o = f4fma(gw.g[3], w3, o);
        o = f4fma(gw.g[4], w4, o);
        o = f4fma(gw.g[5], w5, o);
        o = f4fma(gw.g[6], w6, o);
        o = f4fma(gw.g[7], w7, o);
        o = f4fma(gw.g[8], w8, o);
        st4s(d, o); d += stride;
        w0=w1; w1=w2; w2=w3; w3=w4; w4=w5; w5=w6; w6=w7; w7=w8;
    }
}

// ---------------- fused 2-iteration step ----------------
// Tile: 64 wide x 16 tall. 512 threads. All LDS float4-aligned.
// LDS overlay map (floats):
//   [0,3168)      su   36x88   P1->P2
//   [0,6864)      v1x3 26x88   P3->P4   (overlays su)
//   [6864,15840)  p x3 34x88   P2->P3
//   [6864,8944)   u1   26x80   P4->P7   (overlays p)
//   [8944,14416)  q x3 24x76   P5->P6   (overlays p)
//   [0,3648)      v2x3 16x76   P6->P7   (overlays v1)
__global__ void __launch_bounds__(512, 4) step2_kernel(
        const float* __restrict__ uin, float* __restrict__ uout,
        const float* __restrict__ rho,
        const float* __restrict__ dtp, const float* __restrict__ kp,
        GaussW gw)
{
    __shared__ __align__(16) float lds[15840];
    float* su  = lds;            // 36x88
    float* v1_ = lds;            // 3 x 26x88 (plane stride 2288)
    float* p_  = lds + 6864;     // 3 x 34x88 (plane stride 2992)
    float* u1  = lds + 6864;     // 26x80
    float* q_  = lds + 8944;     // 3 x 24x76 (plane stride 1824)
    float* v2_ = lds;            // 3 x 16x76 (plane stride 1216)

    const int tid = threadIdx.x;
    const int X0 = blockIdx.x * 64, Y0 = blockIdx.y * 16, b = blockIdx.z;
    const float* ub = uin + b*HW;
    const float* rb = rho + b*HW;
    const float dt = *dtp;
    const float kk = *kp;
    const float k2inv = 1.f / (kk * kk);

    // ---- P1: load u window rows [Y0-10,Y0+26) cols [X0-12,X0+76), zero outside
    for (int idx = tid; idx < 36*22; idx += 512) {
        int r = idx / 22, cg = idx - r*22;
        int gy = Y0 - 10 + r, gc = X0 - 12 + 4*cg;
        float4 v = make_float4(0.f,0.f,0.f,0.f);
        if (gy >= 0 && gy < H && gc >= 0 && gc <= W-4) v = ld4s(ub + gy*W + gc);
        st4s(su + r*88 + 4*cg, v);
    }
    __syncthreads();

    // ---- P2: iter1 Sobel products on rows [Y0-9,Y0+25) (row-reflect via refl)
    for (int idx = tid; idx < 34*22; idx += 512) {
        int pr = idx / 22, cg = idx - pr*22;
        int wy = Y0 - 9 + pr;
        int sr = refl(wy, H) - (Y0 - 10);
        const float* rm = su + (sr-1)*88;
        const float* rc = su + sr*88;
        const float* rp = su + (sr+1)*88;
        int qA = 4*cg-4; if (qA < 0) qA = 0;
        int qB = 4*cg;
        int qC = 4*cg+4; if (qC > 84) qC = 84;
        float4 Am = ld4s(rm+qA), Bm = ld4s(rm+qB), Cm = ld4s(rm+qC);
        float4 Ac = ld4s(rc+qA), Bc = ld4s(rc+qB), Cc = ld4s(rc+qC);
        float4 Ap = ld4s(rp+qA), Bp = ld4s(rp+qB), Cp = ld4s(rp+qC);
        float fm[6] = {Am.w, Bm.x, Bm.y, Bm.z, Bm.w, Cm.x};
        float fc[6] = {Ac.w, Bc.x, Bc.y, Bc.z, Bc.w, Cc.x};
        float fp[6] = {Ap.w, Bp.x, Bp.y, Bp.z, Bp.w, Cp.x};
        float o11[4], o12[4], o22[4];
#pragma unroll
        for (int j = 0; j < 4; ++j) {
            float gx = (fm[j+2]-fm[j]) + 2.f*(fc[j+2]-fc[j]) + (fp[j+2]-fp[j]);
            float gy = (fp[j]-fm[j]) + 2.f*(fp[j+1]-fm[j+1]) + (fp[j+2]-fm[j+2]);
            o11[j] = gx*gx; o12[j] = gx*gy; o22[j] = gy*gy;
        }
        int o = pr*88 + 4*cg;
        st4s(p_ + 0*2992 + o, make_float4(o11[0],o11[1],o11[2],o11[3]));
        st4s(p_ + 1*2992 + o, make_float4(o12[0],o12[1],o12[2],o12[3]));
        st4s(p_ + 2*2992 + o, make_float4(o22[0],o22[1],o22[2],o22[3]));
    }
    __syncthreads();

    // ---- P3: iter1 vertical blur, strips {7,7,7,5} over 26 rows
    for (int idx = tid; idx < 3*4*22; idx += 512) {
        int cg = idx % 22; int t = idx / 22; int strip = t & 3; int plane = t >> 2;
        const float* P = p_ + plane*2992;
        float* V = v1_ + plane*2288;
        if (strip == 3) vblur_strip<5>(P, V, 4*cg, 21, gw, 88);
        else            vblur_strip<7>(P, V, 4*cg, strip*7, gw, 88);
    }
    __syncthreads();

    // ---- P3.5: mirror-fill v1 ghost cols (blur col-reflect), edge blocks only
    if (X0 == 0) {
        for (int idx = tid; idx < 3*26*9; idx += 512) {
            int j = idx % 9 + 1; int t = idx / 9; int r = t % 26; int plane = t / 26;
            float* V = v1_ + plane*2288 + r*88;
            V[12 - j] = V[12 + j];
        }
    } else if (X0 == W - 64) {
        for (int idx = tid; idx < 3*26*9; idx += 512) {
            int j = idx % 9 + 1; int t = idx / 9; int r = t % 26; int plane = t / 26;
            float* V = v1_ + plane*2288 + r*88;
            V[75 + j] = V[75 - j];
        }
    }
    __syncthreads();

    // ---- P4: iter1 horizontal blur + eig + update -> u1 (zero outside image)
    for (int idx = tid; idx < 26*20; idx += 512) {
        int r = idx / 20, cg = idx - r*20;
        int uy = Y0 - 5 + r;
        int c0 = X0 - 8 + 4*cg;
        float4 res = make_float4(0.f,0.f,0.f,0.f);
        if (uy >= 0 && uy < H && c0 >= 0 && c0 <= W-4) {
            int qb = 4*cg;
            const float* Vp;
            Vp = v1_ + 0*2288 + r*88 + qb;
            float4 a0 = ld4s(Vp), b0 = ld4s(Vp+4), c0q = ld4s(Vp+8);
            Vp = v1_ + 1*2288 + r*88 + qb;
            float4 a1 = ld4s(Vp), b1 = ld4s(Vp+4), c1q = ld4s(Vp+8);
            Vp = v1_ + 2*2288 + r*88 + qb;
            float4 a2 = ld4s(Vp), b2 = ld4s(Vp+4), c2q = ld4s(Vp+8);
            float f11[12] = {a0.x,a0.y,a0.z,a0.w,b0.x,b0.y,b0.z,b0.w,c0q.x,c0q.y,c0q.z,c0q.w};
            float f12[12] = {a1.x,a1.y,a1.z,a1.w,b1.x,b1.y,b1.z,b1.w,c1q.x,c1q.y,c1q.z,c1q.w};
            float f22[12] = {a2.x,a2.y,a2.z,a2.w,b2.x,b2.y,b2.z,b2.w,c2q.x,c2q.y,c2q.z,c2q.w};
            float4 rv = ld4s(rb + uy*W + c0);
            float4 uq = ld4s(ub + uy*W + c0);
            float rva[4] = {rv.x, rv.y, rv.z, rv.w};
            float uqa[4] = {uq.x, uq.y, uq.z, uq.w};
            float ra[4];
#pragma unroll
            for (int j = 0; j < 4; ++j) {
                float s11 = 0.f, s12 = 0.f, s22 = 0.f;
#pragma unroll
                for (int t = 0; t < 9; ++t) {
                    s11 = fmaf(gw.g[t], f11[j+t], s11);
                    s12 = fmaf(gw.g[t], f12[j+t], s12);
                    s22 = fmaf(gw.g[t], f22[j+t], s22);
                }
                s11 -= rva[j]; s12 -= rva[j]; s22 -= rva[j];
                float df = s11 - s22;
                float tm = sqrtf(df*df + 4.f*s12*s12);
                float sm = s11 + s22;
                float lam1 = 0.5f*(sm + tm);
                float lam2 = 0.5f*(sm - tm);
                float e1 = expf(-lam1*lam1*k2inv);
                float e2 = expf(-lam2*lam2*k2inv);
                ra[j] = uqa[j] + dt*(e1*lam1 + e2*lam2);
            }
            res = make_float4(ra[0], ra[1], ra[2], ra[3]);
        }
        st4s(u1 + r*80 + 4*cg, res);
    }
    __syncthreads();

    // ---- P5: iter2 Sobel products from u1, rows [Y0-4,Y0+20)
    for (int idx = tid; idx < 24*19; idx += 512) {
        int pr = idx / 19, cg = idx - pr*19;
        int wy = Y0 - 4 + pr;
        int ur = refl(wy, H) - (Y0 - 5);
        const float* rm = u1 + (ur-1)*80;
        const float* rc = u1 + ur*80;
        const float* rp = u1 + (ur+1)*80;
        int qA = 4*cg-4; if (qA < 0) qA = 0;
        int qB = 4*cg;
        int qC = 4*cg+4; if (qC > 76) qC = 76;
        float4 Am = ld4s(rm+qA), Bm = ld4s(rm+qB), Cm = ld4s(rm+qC);
        float4 Ac = ld4s(rc+qA), Bc = ld4s(rc+qB), Cc = ld4s(rc+qC);
        float4 Ap = ld4s(rp+qA), Bp = ld4s(rp+qB), Cp = ld4s(rp+qC);
        float fm[6] = {Am.w, Bm.x, Bm.y, Bm.z, Bm.w, Cm.x};
        float fc[6] = {Ac.w, Bc.x, Bc.y, Bc.z, Bc.w, Cc.x};
        float fp[6] = {Ap.w, Bp.x, Bp.y, Bp.z, Bp.w, Cp.x};
        float o11[4], o12[4], o22[4];
#pragma unroll
        for (int j = 0; j < 4; ++j) {
            float gx = (fm[j+2]-fm[j]) + 2.f*(fc[j+2]-fc[j]) + (fp[j+2]-fp[j]);
            float gy = (fp[j]-fm[j]) + 2.f*(fp[j+1]-fm[j+1]) + (fp[j+2]-fm[j+2]);
            o11[j] = gx*gx; o12[j] = gx*gy; o22[j] = gy*gy;
        }
        int o = pr*76 + 4*cg;
        st4s(q_ + 0*1824 + o, make_float4(o11[0],o11[1],o11[2],o11[3]));
        st4s(q_ + 1*1824 + o, make_float4(o12[0],o12[1],o12[2],o12[3]));
        st4s(q_ + 2*1824 + o, make_float4(o22[0],o22[1],o22[2],o22[3]));
    }
    __syncthreads();

    // ---- P6: iter2 vertical blur, strips {8,8} over 16 rows
    for (int idx = tid; idx < 3*2*19; idx += 512) {
        int cg = idx % 19; int t = idx / 19; int strip = t & 1; int plane = t >> 1;
        const float* P = q_ + plane*1824;
        float* V = v2_ + plane*1216;
        vblur_strip<8>(P, V, 4*cg, strip*8, gw, 76);
    }
    __syncthreads();

    // ---- P6.5: mirror-fill v2 ghost cols, edge blocks only
    if (X0 == 0) {
        for (int idx = tid; idx < 3*16*4; idx += 512) {
            int j = idx % 4 + 1; int t = idx / 4; int r = t % 16; int plane = t / 16;
            float* V = v2_ + plane*1216 + r*76;
            V[8 - j] = V[8 + j];
        }
    } else if (X0 == W - 64) {
        for (int idx = tid; idx < 3*16*4; idx += 512) {
            int j = idx % 4 + 1; int t = idx / 4; int r = t % 16; int plane = t / 16;
            float* V = v2_ + plane*1216 + r*76;
            V[71 + j] = V[71 - j];
        }
    }
    __syncthreads();

    // ---- P7: iter2 horizontal blur + eig + update -> global
    float* ob = uout + b*HW;
    for (int idx = tid; idx < 16*16; idx += 512) {
        int r = idx >> 4, cg = idx & 15;
        int c0 = X0 + 4*cg;
        int qb = 4*cg + 4;
        const float* Vp;
        Vp = v2_ + 0*1216 + r*76 + qb;
        float4 a0 = ld4s(Vp), b0 = ld4s(Vp+4), c0q = ld4s(Vp+8);
        Vp = v2_ + 1*1216 + r*76 + qb;
        float4 a1 = ld4s(Vp), b1 = ld4s(Vp+4), c1q = ld4s(Vp+8);
        Vp = v2_ + 2*1216 + r*76 + qb;
        float4 a2 = ld4s(Vp), b2 = ld4s(Vp+4), c2q = ld4s(Vp+8);
        float f11[12] = {a0.x,a0.y,a0.z,a0.w,b0.x,b0.y,b0.z,b0.w,c0q.x,c0q.y,c0q.z,c0q.w};
        float f12[12] = {a1.x,a1.y,a1.z,a1.w,b1.x,b1.y,b1.z,b1.w,c1q.x,c1q.y,c1q.z,c1q.w};
        float f22[12] = {a2.x,a2.y,a2.z,a2.w,b2.x,b2.y,b2.z,b2.w,c2q.x,c2q.y,c2q.z,c2q.w};
        float4 rv = ld4s(rb + (Y0+r)*W + c0);
        float4 uq = ld4s(u1 + (r+5)*80 + 4*cg + 8);
        float rva[4] = {rv.x, rv.y, rv.z, rv.w};
        float uqa[4] = {uq.x, uq.y, uq.z, uq.w};
        float ra[4];
#pragma unroll
        for (int j = 0; j < 4; ++j) {
            float s11 = 0.f, s12 = 0.f, s22 = 0.f;
#pragma unroll
            for (int t = 0; t < 9; ++t) {
                s11 = fmaf(gw.g[t], f11[j+t], s11);
                s12 = fmaf(gw.g[t], f12[j+t], s12);
                s22 = fmaf(gw.g[t], f22[j+t], s22);
            }
            s11 -= rva[j]; s12 -= rva[j]; s22 -= rva[j];
            float df = s11 - s22;
            float tm = sqrtf(df*df + 4.f*s12*s12);
            float sm = s11 + s22;
            float lam1 = 0.5f*(sm + tm);
            float lam2 = 0.5f*(sm - tm);
            float e1 = expf(-lam1*lam1*k2inv);
            float e2 = expf(-lam2*lam2*k2inv);
            ra[j] = uqa[j] + dt*(e1*lam1 + e2*lam2);
        }
        st4s(ob + (Y0+r)*W + c0, make_float4(ra[0], ra[1], ra[2], ra[3]));
    }
}

extern "C" void kernel_launch(void* const* d_in, const int* in_sizes, int n_in,
                              void* d_out, int out_size, void* d_ws, size_t ws_size,
                              hipStream_t stream) {
    const float* x   = (const float*)d_in[0];
    const float* dtp = (const float*)d_in[1];
    const float* kp  = (const float*)d_in[2];
    float* out = (float*)d_out;

    float* u_a = (float*)d_ws;
    float* u_b = u_a + BATCH*HW;
    float* rho = u_b + BATCH*HW;

    GaussW gw;
    {
        double s = 0.0, wd[KS];
        for (int i = 0; i < KS; ++i) {
            double xd = (double)i - 4.0;
            wd[i] = exp(-0.5 * (xd/4.0) * (xd/4.0));
            s += wd[i];
        }
        for (int i = 0; i < KS; ++i) gw.g[i] = (float)(wd[i] / s);
    }

    dim3 b1(256), g1((BATCH*HW + 255)/256);
    luma_kernel<<<g1, b1, 0, stream>>>(x, u_a);
    vblur_kernel<<<g1, b1, 0, stream>>>(u_a, u_b, gw);   // u_b as tmp
    hblur_kernel<<<g1, b1, 0, stream>>>(u_b, rho, gw);

    dim3 gs(W/64, H/16, BATCH), bs(512);
    float* cur = u_a;
    float* nxt = u_b;
    for (int it = 0; it < NSTEP; ++it) {
        step2_kernel<<<gs, bs, 0, stream>>>(cur, nxt, rho, dtp, kp, gw);
        float* t = cur; cur = nxt; nxt = t;
    }
    expand_kernel<<<g1, b1, 0, stream>>>(cur, out);
}